// Round 2
// baseline (249.408 us; speedup 1.0000x reference)
//
#include <hip/hip_runtime.h>
#include <hip/hip_bf16.h>
#include <stdint.h>

#define N_TOK 8192
#define DDIM 1024
#define FDIM 4096
#define NEXP 8

typedef __attribute__((ext_vector_type(8))) short short8;
typedef __attribute__((ext_vector_type(4))) float f32x4;

#define SCHED_FENCE __builtin_amdgcn_sched_barrier(0)
#define CFENCE asm volatile("" ::: "memory")
#define HWBAR __builtin_amdgcn_s_barrier()

__device__ __forceinline__ ushort f2bf(float f) {
  uint32_t u = __float_as_uint(f);
  u += 0x7FFF + ((u >> 16) & 1);   // RNE
  return (ushort)(u >> 16);
}

__device__ __forceinline__ void gload16(const void* g, void* l) {
  __builtin_amdgcn_global_load_lds((const __attribute__((address_space(1))) void*)g,
                                   (__attribute__((address_space(3))) void*)l, 16, 0, 0);
}

// ---------- cast f32 -> bf16 ----------
__global__ __launch_bounds__(256) void cast_kernel(const float* __restrict__ in,
                                                   ushort* __restrict__ out, int n4) {
  int i = blockIdx.x * 256 + threadIdx.x;
  if (i >= n4) return;
  float4 v = reinterpret_cast<const float4*>(in)[i];
  ushort4 o;
  o.x = f2bf(v.x); o.y = f2bf(v.y); o.z = f2bf(v.z); o.w = f2bf(v.w);
  reinterpret_cast<ushort4*>(out)[i] = o;
}

// ---------- router (unchanged; passed round 1) ----------
__global__ __launch_bounds__(256) void router_kernel(
    const float* __restrict__ x, const float* __restrict__ gW, const float* __restrict__ gb,
    const float* __restrict__ lA, int* __restrict__ top1, float* __restrict__ coeff,
    ushort* __restrict__ xb) {
  const int lane = threadIdx.x & 63;
  const int wid = threadIdx.x >> 6;
  const int tok = blockIdx.x * 4 + wid;
  const float* xp = x + (size_t)tok * DDIM;
  float4 xv[4];
#pragma unroll
  for (int i = 0; i < 4; ++i)
    xv[i] = *reinterpret_cast<const float4*>(xp + i * 256 + lane * 4);
#pragma unroll
  for (int i = 0; i < 4; ++i) {
    ushort4 o;
    o.x = f2bf(xv[i].x); o.y = f2bf(xv[i].y); o.z = f2bf(xv[i].z); o.w = f2bf(xv[i].w);
    *reinterpret_cast<ushort4*>(xb + (size_t)tok * DDIM + i * 256 + lane * 4) = o;
  }
  double lg[NEXP];
#pragma unroll
  for (int e = 0; e < NEXP; ++e) {
    const float* gp = gW + e * DDIM;
    double s = 0.0;
#pragma unroll
    for (int i = 0; i < 4; ++i) {
      float4 g = *reinterpret_cast<const float4*>(gp + i * 256 + lane * 4);
      s += (double)xv[i].x * g.x + (double)xv[i].y * g.y +
           (double)xv[i].z * g.z + (double)xv[i].w * g.w;
    }
    lg[e] = s;
  }
#pragma unroll
  for (int e = 0; e < NEXP; ++e)
    for (int off = 32; off > 0; off >>= 1) lg[e] += __shfl_xor(lg[e], off);
  int best = 0;
  double bv = lg[0] + (double)gb[0];
#pragma unroll
  for (int e = 1; e < NEXP; ++e) {
    double v = lg[e] + (double)gb[e];
    if (v > bv) { bv = v; best = e; }
  }
  float c[4];
#pragma unroll
  for (int r = 0; r < 4; ++r) {
    const float* ap = lA + ((size_t)best * 4 + r) * DDIM;
    float s = 0.f;
#pragma unroll
    for (int i = 0; i < 4; ++i) {
      float4 a = *reinterpret_cast<const float4*>(ap + i * 256 + lane * 4);
      s = fmaf(xv[i].x, a.x, s); s = fmaf(xv[i].y, a.y, s);
      s = fmaf(xv[i].z, a.z, s); s = fmaf(xv[i].w, a.w, s);
    }
    for (int off = 32; off > 0; off >>= 1) s += __shfl_xor(s, off);
    c[r] = s;
  }
  if (lane == 0) {
    top1[tok] = best;
    float4 cc; cc.x = c[0]; cc.y = c[1]; cc.z = c[2]; cc.w = c[3];
    *reinterpret_cast<float4*>(coeff + tok * 4) = cc;
  }
}

// =====================================================================
// GEMM1: inter = relu(xb[8192,1024] @ wiWb[4096,1024]^T + wi_b + lora)
// 256x256 tile, BK=32, 8 waves (2Mx4N), 4-slot LDS ring, 2-tile lookahead.
// LDS per slot: A chunk-major [4][256] of 16B units (16KB) + B same (16KB).
// =====================================================================
__global__ __launch_bounds__(512, 2) void gemm1_kernel(
    const ushort* __restrict__ A, const ushort* __restrict__ B,
    const float* __restrict__ bias, const int* __restrict__ top1,
    const float4* __restrict__ coeff, const float4* __restrict__ loraB,
    ushort* __restrict__ C) {
  __shared__ __align__(16) ushort lds[65536];     // 4 slots * 16384 ushorts = 128 KiB
  const int tid = threadIdx.x;
  const int lane = tid & 63;
  const int wid = tid >> 6;
  const int wr = wid >> 2, wc = wid & 3;          // 2M x 4N waves

  // XCD swizzle + block decompose (nwg=512, %8==0)
  int bid = blockIdx.x;
  int swz = (bid & 7) * 64 + (bid >> 3);
  const int brow = swz >> 4;                      // 32 m-blocks
  const int bcol = swz & 15;                      // 16 n-blocks

  const int NT = DDIM / 32;                       // 32 k-tiles

  // staging source pointers (per-thread)
  const int rs = tid & 255, ch = tid >> 8;        // ch in {0,1}
  const ushort* gA0 = A + (size_t)(brow * 256 + rs) * DDIM + ch * 8;   // chunks ch
  const ushort* gA1 = gA0 + 16;                                         // chunks 2+ch
  const ushort* gB0 = B + (size_t)(bcol * 256 + rs) * DDIM + ch * 8;
  const ushort* gB1 = gB0 + 16;
  ushort* const sdst = lds + tid * 8;             // + slot*16384 + round*4096

  // ds_read base offsets (ushort units)
  const int cA = lane >> 4, rlo = lane & 15;
  const int aoff = ((cA << 8) + wr * 128 + rlo) * 8;          // + (h*4+fm)*128
  const int boff = 8192 + ((cA << 8) + wc * 64 + rlo) * 8;    // + fn*128

  f32x4 acc[8][4] = {};

  // prologue: stage tiles 0 (slot0) and 1 (slot1)
  gload16(gA0,      sdst);                 gload16(gA1,      sdst + 4096);
  gload16(gB0,      sdst + 8192);          gload16(gB1,      sdst + 12288);
  gload16(gA0 + 32, sdst + 16384);         gload16(gA1 + 32, sdst + 16384 + 4096);
  gload16(gB0 + 32, sdst + 16384 + 8192);  gload16(gB1 + 32, sdst + 16384 + 12288);
  asm volatile("s_waitcnt vmcnt(4)" ::: "memory");
  SCHED_FENCE; HWBAR; SCHED_FENCE;

#pragma unroll 1
  for (int t = 0; t < NT; ++t) {
    const ushort* sp = lds + (t & 3) * 16384;
    const int t2 = t + 2;
    ushort* s2 = sdst + (t2 & 3) * 16384;
    const int k2 = t2 * 32;
    short8 a0[4], b0[4];
    // ---- phase 0: read A(h=0) + B, stage A of tile t+2 ----
    CFENCE;
#pragma unroll
    for (int fm = 0; fm < 4; ++fm)
      a0[fm] = *reinterpret_cast<const short8*>(sp + aoff + fm * 128);
#pragma unroll
    for (int fn = 0; fn < 4; ++fn)
      b0[fn] = *reinterpret_cast<const short8*>(sp + boff + fn * 128);
    if (t2 < NT) { gload16(gA0 + k2, s2); gload16(gA1 + k2, s2 + 4096); }
    CFENCE; SCHED_FENCE; HWBAR; SCHED_FENCE;
    __builtin_amdgcn_s_setprio(1);
#pragma unroll
    for (int fn = 0; fn < 4; ++fn)
#pragma unroll
      for (int fm = 0; fm < 4; ++fm)
        acc[fm][fn] = __builtin_amdgcn_mfma_f32_16x16x32_bf16(a0[fm], b0[fn], acc[fm][fn], 0, 0, 0);
    __builtin_amdgcn_s_setprio(0);
    SCHED_FENCE; CFENCE; HWBAR; SCHED_FENCE;
    // ---- phase 1: read A(h=1), stage B of tile t+2, tile-end wait ----
    CFENCE;
#pragma unroll
    for (int fm = 0; fm < 4; ++fm)
      a0[fm] = *reinterpret_cast<const short8*>(sp + aoff + 512 + fm * 128);
    if (t2 < NT) { gload16(gB0 + k2, s2 + 8192); gload16(gB1 + k2, s2 + 12288); }
    CFENCE; SCHED_FENCE; HWBAR; SCHED_FENCE;
    __builtin_amdgcn_s_setprio(1);
#pragma unroll
    for (int fn = 0; fn < 4; ++fn)
#pragma unroll
      for (int fm = 0; fm < 4; ++fm)
        acc[4 + fm][fn] = __builtin_amdgcn_mfma_f32_16x16x32_bf16(a0[fm], b0[fn], acc[4 + fm][fn], 0, 0, 0);
    __builtin_amdgcn_s_setprio(0);
    SCHED_FENCE;
    if (t2 < NT) asm volatile("s_waitcnt vmcnt(4)" ::: "memory");
    else         asm volatile("s_waitcnt vmcnt(0)" ::: "memory");
    HWBAR; SCHED_FENCE;
  }

  // ---- epilogue: stage lora/coeff/top1 into LDS, then fused bias+lora+relu ----
  __syncthreads();
  char* lb = (char*)lds;
  float4* lora_s  = (float4*)lb;             // [8][256] = 32 KB
  float4* coeff_s = (float4*)(lb + 32768);   // [256]    =  4 KB
  int*    top1_s  = (int*)  (lb + 36864);    // [256]    =  1 KB
#pragma unroll
  for (int i = 0; i < 4; ++i) {
    int idx = tid + i * 512;                 // idx>>8 = expert, idx&255 = col
    lora_s[idx] = loraB[(size_t)(idx >> 8) * FDIM + bcol * 256 + (idx & 255)];
  }
  if (tid < 256) {
    coeff_s[tid] = coeff[brow * 256 + tid];
    top1_s[tid]  = top1[brow * 256 + tid];
  }
  __syncthreads();

  const int ccb = wc * 64 + (lane & 15);
  float bias4[4];
#pragma unroll
  for (int fn = 0; fn < 4; ++fn) bias4[fn] = bias[bcol * 256 + ccb + fn * 16];
#pragma unroll
  for (int fm = 0; fm < 8; ++fm) {
#pragma unroll
    for (int q = 0; q < 4; ++q) {
      const int tl = wr * 128 + fm * 16 + ((lane >> 4) << 2) + q;
      const int e = top1_s[tl];
      const float4 cf = coeff_s[tl];
      ushort* crow = C + (size_t)(brow * 256 + tl) * FDIM + bcol * 256;
#pragma unroll
      for (int fn = 0; fn < 4; ++fn) {
        const int cc = ccb + fn * 16;
        const float4 l4 = lora_s[e * 256 + cc];
        float v = acc[fm][fn][q] + bias4[fn] +
                  cf.x * l4.x + cf.y * l4.y + cf.z * l4.z + cf.w * l4.w;
        crow[cc] = f2bf(fmaxf(v, 0.f));
      }
    }
  }
}

// =====================================================================
// GEMM2: out = inter[8192,4096] @ woWb[1024,4096]^T + wo_b   (f32 out)
// 128x256 tile, BK=32, 8 waves (2Mx4N, wave 64x64), 4-slot ring.
// LDS slot: A [4][128] units (8KB) + B [4][256] units (16KB) = 24KB; 4 slots = 96KB
// =====================================================================
__global__ __launch_bounds__(512, 2) void gemm2_kernel(
    const ushort* __restrict__ A, const ushort* __restrict__ B,
    const float* __restrict__ bias, float* __restrict__ C) {
  __shared__ __align__(16) ushort lds[49152];
  const int tid = threadIdx.x;
  const int lane = tid & 63;
  const int wid = tid >> 6;
  const int wr = wid >> 2, wc = wid & 3;

  int bid = blockIdx.x;                       // nwg = 256
  int swz = (bid & 7) * 32 + (bid >> 3);
  const int brow = swz >> 2;                  // 64 m-blocks
  const int bcol = swz & 3;                   // 4 n-blocks

  const int NT = FDIM / 32;                   // 128 k-tiles

  const int rsA = tid & 127, chA = tid >> 7;
  const ushort* gA = A + (size_t)(brow * 128 + rsA) * FDIM + chA * 8;
  const int rs = tid & 255, ch = tid >> 8;
  const ushort* gB0 = B + (size_t)(bcol * 256 + rs) * FDIM + ch * 8;
  const ushort* gB1 = gB0 + 16;
  ushort* const sdst = lds + tid * 8;         // + slot*12288 (+4096/+8192 for B rounds)

  const int cA = lane >> 4, rlo = lane & 15;
  const int aoff = ((cA << 7) + wr * 64 + rlo) * 8;           // + (h*2+fm)*128
  const int boff = 4096 + ((cA << 8) + wc * 64 + rlo) * 8;    // + fn*128

  f32x4 acc[4][4] = {};

  // prologue: tiles 0,1
  gload16(gA,       sdst);
  gload16(gB0,      sdst + 4096);          gload16(gB1,      sdst + 8192);
  gload16(gA + 32,  sdst + 12288);
  gload16(gB0 + 32, sdst + 12288 + 4096);  gload16(gB1 + 32, sdst + 12288 + 8192);
  asm volatile("s_waitcnt vmcnt(3)" ::: "memory");
  SCHED_FENCE; HWBAR; SCHED_FENCE;

#pragma unroll 1
  for (int t = 0; t < NT; ++t) {
    const ushort* sp = lds + (t & 3) * 12288;
    const int t2 = t + 2;
    ushort* s2 = sdst + (t2 & 3) * 12288;
    const int k2 = t2 * 32;
    short8 a0[2], b0[4];
    // ---- phase 0 ----
    CFENCE;
#pragma unroll
    for (int fm = 0; fm < 2; ++fm)
      a0[fm] = *reinterpret_cast<const short8*>(sp + aoff + fm * 128);
#pragma unroll
    for (int fn = 0; fn < 4; ++fn)
      b0[fn] = *reinterpret_cast<const short8*>(sp + boff + fn * 128);
    if (t2 < NT) { gload16(gA + k2, s2); gload16(gB0 + k2, s2 + 4096); }
    CFENCE; SCHED_FENCE; HWBAR; SCHED_FENCE;
    __builtin_amdgcn_s_setprio(1);
#pragma unroll
    for (int fn = 0; fn < 4; ++fn)
#pragma unroll
      for (int fm = 0; fm < 2; ++fm)
        acc[fm][fn] = __builtin_amdgcn_mfma_f32_16x16x32_bf16(a0[fm], b0[fn], acc[fm][fn], 0, 0, 0);
    __builtin_amdgcn_s_setprio(0);
    SCHED_FENCE; CFENCE; HWBAR; SCHED_FENCE;
    // ---- phase 1 ----
    CFENCE;
#pragma unroll
    for (int fm = 0; fm < 2; ++fm)
      a0[fm] = *reinterpret_cast<const short8*>(sp + aoff + 256 + fm * 128);
    if (t2 < NT) gload16(gB1 + k2, s2 + 8192);
    CFENCE; SCHED_FENCE; HWBAR; SCHED_FENCE;
    __builtin_amdgcn_s_setprio(1);
#pragma unroll
    for (int fn = 0; fn < 4; ++fn)
#pragma unroll
      for (int fm = 0; fm < 2; ++fm)
        acc[2 + fm][fn] = __builtin_amdgcn_mfma_f32_16x16x32_bf16(a0[fm], b0[fn], acc[2 + fm][fn], 0, 0, 0);
    __builtin_amdgcn_s_setprio(0);
    SCHED_FENCE;
    if (t2 < NT) asm volatile("s_waitcnt vmcnt(3)" ::: "memory");
    else         asm volatile("s_waitcnt vmcnt(0)" ::: "memory");
    HWBAR; SCHED_FENCE;
  }

  const int ccb = wc * 64 + (lane & 15);
  float bias4[4];
#pragma unroll
  for (int fn = 0; fn < 4; ++fn) bias4[fn] = bias[bcol * 256 + ccb + fn * 16];
#pragma unroll
  for (int fm = 0; fm < 4; ++fm) {
#pragma unroll
    for (int q = 0; q < 4; ++q) {
      const int tl = wr * 64 + fm * 16 + ((lane >> 4) << 2) + q;
      float* crow = C + (size_t)(brow * 128 + tl) * DDIM + bcol * 256;
#pragma unroll
      for (int fn = 0; fn < 4; ++fn)
        crow[ccb + fn * 16] = acc[fm][fn][q] + bias4[fn];
    }
  }
}

extern "C" void kernel_launch(void* const* d_in, const int* in_sizes, int n_in,
                              void* d_out, int out_size, void* d_ws, size_t ws_size,
                              hipStream_t stream) {
  const float* x      = (const float*)d_in[0];
  const float* gate_W = (const float*)d_in[1];
  const float* gate_b = (const float*)d_in[2];
  const float* wi_W   = (const float*)d_in[3];
  const float* wi_b   = (const float*)d_in[4];
  const float* wo_W   = (const float*)d_in[5];
  const float* wo_b   = (const float*)d_in[6];
  const float* lora_A = (const float*)d_in[7];
  const float* lora_B = (const float*)d_in[8];
  float* out = (float*)d_out;

  char* ws = (char*)d_ws;
  ushort* xb    = (ushort*)(ws);                       // 16.78 MB
  ushort* wiWb  = (ushort*)(ws + 16777216);            //  8.39 MB
  ushort* woWb  = (ushort*)(ws + 25165824);            //  8.39 MB
  ushort* inter = (ushort*)(ws + 33554432);            // 67.1  MB
  int*    top1  = (int*)   (ws + 100663296);           // 32 KB
  float*  coeff = (float*) (ws + 100696064);           // 128 KB

  cast_kernel<<<4096, 256, 0, stream>>>(wi_W, wiWb, FDIM * DDIM / 4);
  cast_kernel<<<4096, 256, 0, stream>>>(wo_W, woWb, DDIM * FDIM / 4);
  router_kernel<<<N_TOK / 4, 256, 0, stream>>>(x, gate_W, gate_b, lora_A, top1, coeff, xb);
  gemm1_kernel<<<512, 512, 0, stream>>>(
      xb, wiWb, wi_b, top1, (const float4*)coeff, (const float4*)lora_B, inter);
  gemm2_kernel<<<256, 512, 0, stream>>>(inter, woWb, wo_b, out);
}